// Round 1
// baseline (767.276 us; speedup 1.0000x reference)
//
#include <hip/hip_runtime.h>

#define N_NODES 100000
#define N_EDGES 1600000
#define HID 64
#define BN_EPS 1e-5f

// ---------------- init: deg=1 (self loop), win=-1, hist=0, counter=0, bn acc=0
__global__ void init_kernel(float* deg, int* win, int* hist, int* counter, float* bnacc) {
    int v = blockIdx.x * blockDim.x + threadIdx.x;
    if (v < N_NODES) { deg[v] = 1.0f; win[v] = -1; hist[v] = 0; }
    if (v == 0) *counter = 0;
    if (v < 256) bnacc[v] = 0.0f;   // [layer][sum64|sq64] x2 layers
}

// ---------------- edge pass 1: degree, last-write-wins key, in-degree histogram
__global__ void edge_pass1(const int* __restrict__ src, const int* __restrict__ dst,
                           const float* __restrict__ attr,
                           float* deg, int* win, int* hist) {
    int i = blockIdx.x * blockDim.x + threadIdx.x;
    if (i >= N_EDGES) return;
    int s = src[i], d = dst[i];
    float a = attr[i];
    atomicAdd(&deg[d], a);
    atomicMax(&win[s], i);            // src writes: priority i
    atomicMax(&win[d], N_EDGES + i);  // dst writes: priority E+i (dst beats src)
    atomicAdd(&hist[d], 1);
}

// ---------------- node pass: dinv + unordered CSR segment allocation (wave scan)
__global__ void node_alloc(const float* __restrict__ deg, const int* __restrict__ hist,
                           float* dinv, int* start, int* fillpos, int* counter) {
    int v = blockIdx.x * blockDim.x + threadIdx.x;
    int lane = threadIdx.x & 63;
    int val = (v < N_NODES) ? hist[v] : 0;
    if (v < N_NODES) dinv[v] = rsqrtf(deg[v]);   // deg >= 1 always
    int x = val;
    #pragma unroll
    for (int off = 1; off < 64; off <<= 1) {
        int y = __shfl_up(x, off, 64);
        if (lane >= off) x += y;
    }
    int total = __shfl(x, 63, 64);
    int base = 0;
    if (lane == 63) base = atomicAdd(counter, total);
    base = __shfl(base, 63, 64);
    if (v < N_NODES) {
        int st = base + x - val;   // exclusive within wave
        start[v] = st;
        fillpos[v] = st;
    }
}

// ---------------- edge pass 2: fill CSR (col=src, nrm = dinv[s]*attr*dinv[d])
__global__ void edge_fill(const int* __restrict__ src, const int* __restrict__ dst,
                          const float* __restrict__ attr, const float* __restrict__ dinv,
                          int* fillpos, int* col, float* nrm) {
    int i = blockIdx.x * blockDim.x + threadIdx.x;
    if (i >= N_EDGES) return;
    int s = src[i], d = dst[i];
    int p = atomicAdd(&fillpos[d], 1);
    col[p] = s;
    nrm[p] = dinv[s] * attr[i] * dinv[d];
}

// ---------------- 64x64 GEMM, wave-per-row, W columns in registers
// MODE 0: input projection + fused last-write-wins node update (relu(h0 + a*ew + eb))
// MODE 1: plain Y = X @ W (no bias; conv bias added post-aggregation)
template<int MODE>
__launch_bounds__(256)
__global__ void gemm64(const float* __restrict__ X, const float* __restrict__ W,
                       const float* __restrict__ bias, float* __restrict__ Y,
                       const int* __restrict__ win, const float* __restrict__ attr,
                       const float* __restrict__ ew, const float* __restrict__ eb) {
    __shared__ float xs[32 * 64];          // 32 rows staged, 8 KB
    int t = threadIdx.x;
    int lane = t & 63;
    int w = t >> 6;
    float wc[64];
    #pragma unroll
    for (int k = 0; k < 64; ++k) wc[k] = W[k * 64 + lane];   // coalesced, L1-resident

    int base = blockIdx.x * 32;            // N divisible by 32 -> no tail
    const float4* Xv = (const float4*)(X + (size_t)base * 64);
    float4* xsv = (float4*)xs;
    xsv[t] = Xv[t];
    xsv[t + 256] = Xv[t + 256];
    __syncthreads();

    float bval = 0.0f, ewv = 0.0f, ebv = 0.0f;
    if (MODE == 0) { bval = bias[lane]; ewv = ew[lane]; ebv = eb[lane]; }

    for (int rr = 0; rr < 8; ++rr) {
        int rl = w * 8 + rr;
        int r = base + rl;
        float acc = bval;
        #pragma unroll
        for (int k = 0; k < 64; ++k)
            acc = fmaf(xs[rl * 64 + k], wc[k], acc);   // LDS broadcast read
        if (MODE == 0) {
            int wi = win[r];
            if (wi >= 0) {
                float a = attr[wi >= N_EDGES ? wi - N_EDGES : wi];
                acc = fmaxf(acc + a * ewv + ebv, 0.0f);
            }
        }
        Y[(size_t)r * 64 + lane] = acc;
    }
}

// ---------------- wave-per-node gather: agg = conv_b + dinv^2*xw[v] + sum nrm*xw[src]
__launch_bounds__(256)
__global__ void gather_kernel(const float* __restrict__ xw, const int* __restrict__ col,
                              const float* __restrict__ nrm, const int* __restrict__ start,
                              const int* __restrict__ hist, const float* __restrict__ dinv,
                              const float* __restrict__ convb, float* __restrict__ agg) {
    int t = threadIdx.x;
    int lane = t & 63;
    int w = t >> 6;
    int v = blockIdx.x * 4 + w;
    if (v >= N_NODES) return;
    float dv = dinv[v];
    float acc  = fmaf(dv * dv, xw[(size_t)v * 64 + lane], convb[lane]);
    float acc2 = 0.0f;
    int s0 = start[v];
    int len = hist[v];
    for (int e0 = 0; e0 < len; e0 += 64) {
        int m = len - e0; if (m > 64) m = 64;
        int sc = 0; float wn = 0.0f;
        if (lane < m) { sc = col[s0 + e0 + lane]; wn = nrm[s0 + e0 + lane]; }
        int j = 0;
        for (; j + 3 < m; j += 4) {
            int sA = __shfl(sc, j, 64);     float wA = __shfl(wn, j, 64);
            int sB = __shfl(sc, j + 1, 64); float wB = __shfl(wn, j + 1, 64);
            int sC = __shfl(sc, j + 2, 64); float wC = __shfl(wn, j + 2, 64);
            int sD = __shfl(sc, j + 3, 64); float wD = __shfl(wn, j + 3, 64);
            float xA = xw[(size_t)sA * 64 + lane];
            float xB = xw[(size_t)sB * 64 + lane];
            float xC = xw[(size_t)sC * 64 + lane];
            float xD = xw[(size_t)sD * 64 + lane];
            acc  = fmaf(wA, xA, acc);
            acc2 = fmaf(wB, xB, acc2);
            acc  = fmaf(wC, xC, acc);
            acc2 = fmaf(wD, xD, acc2);
        }
        for (; j < m; ++j) {
            int sA = __shfl(sc, j, 64); float wA = __shfl(wn, j, 64);
            acc = fmaf(wA, xw[(size_t)sA * 64 + lane], acc);
        }
    }
    agg[(size_t)v * 64 + lane] = acc + acc2;
}

// ---------------- BN stats: per-feature sum & sumsq, hierarchical
__launch_bounds__(256)
__global__ void bn_stats(const float* __restrict__ agg, float* __restrict__ bnacc) {
    int t = threadIdx.x; int lane = t & 63; int w = t >> 6;
    float s = 0.f, q = 0.f;
    for (int r = blockIdx.x * 4 + w; r < N_NODES; r += gridDim.x * 4) {
        float v = agg[(size_t)r * 64 + lane];
        s += v; q += v * v;
    }
    __shared__ float red[2][4][64];
    red[0][w][lane] = s; red[1][w][lane] = q;
    __syncthreads();
    if (w == 0) {
        s = red[0][0][lane] + red[0][1][lane] + red[0][2][lane] + red[0][3][lane];
        q = red[1][0][lane] + red[1][1][lane] + red[1][2][lane] + red[1][3][lane];
        atomicAdd(&bnacc[lane], s);
        atomicAdd(&bnacc[64 + lane], q);
    }
}

// ---------------- BN apply (+relu & h-write for layer 0), strided out write
template<int LAYER0>
__launch_bounds__(256)
__global__ void bn_apply(const float* __restrict__ agg, const float* __restrict__ bnacc,
                         const float* __restrict__ gamma, const float* __restrict__ beta,
                         float* __restrict__ out, float* __restrict__ h) {
    int idx = blockIdx.x * 256 + threadIdx.x;
    int c = idx & 63; int v = idx >> 6;
    if (v >= N_NODES) return;
    const float invN = 1.0f / (float)N_NODES;
    float mean = bnacc[c] * invN;
    float var = bnacc[64 + c] * invN - mean * mean;
    float inv = rsqrtf(var + BN_EPS);
    float scale = gamma[c] * inv;
    float bias = beta[c] - mean * scale;
    float val = fmaf(agg[idx], scale, bias);
    if (LAYER0) {
        val = fmaxf(val, 0.0f);
        h[idx] = val;
        out[(size_t)v * 128 + c] = val;
    } else {
        out[(size_t)v * 128 + 64 + c] = val;
    }
}

extern "C" void kernel_launch(void* const* d_in, const int* in_sizes, int n_in,
                              void* d_out, int out_size, void* d_ws, size_t ws_size,
                              hipStream_t stream) {
    const float* x      = (const float*)d_in[0];
    const int*   eidx   = (const int*)d_in[1];
    const float* attr   = (const float*)d_in[2];
    const float* lin_W  = (const float*)d_in[3];
    const float* lin_b  = (const float*)d_in[4];
    const float* eenc_w = (const float*)d_in[5];
    const float* eenc_b = (const float*)d_in[6];
    const float* conv_W = (const float*)d_in[7];
    const float* conv_b = (const float*)d_in[8];
    const float* gamma  = (const float*)d_in[9];
    const float* beta   = (const float*)d_in[10];
    float* out = (float*)d_out;

    const int* src = eidx;
    const int* dst = eidx + N_EDGES;

    // workspace carve (all 16B-aligned sizes)
    char* p = (char*)d_ws;
    float* h    = (float*)p; p += (size_t)N_NODES * 64 * 4;
    float* xw   = (float*)p; p += (size_t)N_NODES * 64 * 4;
    float* agg  = (float*)p; p += (size_t)N_NODES * 64 * 4;
    float* deg  = (float*)p; p += (size_t)N_NODES * 4;
    float* dinv = (float*)p; p += (size_t)N_NODES * 4;
    int* win    = (int*)p;   p += (size_t)N_NODES * 4;
    int* hist   = (int*)p;   p += (size_t)N_NODES * 4;
    int* start  = (int*)p;   p += (size_t)N_NODES * 4;
    int* fpos   = (int*)p;   p += (size_t)N_NODES * 4;
    int* col    = (int*)p;   p += (size_t)N_EDGES * 4;
    float* nrm  = (float*)p; p += (size_t)N_EDGES * 4;
    int* counter = (int*)p;  p += 16;
    float* bnacc = (float*)p; p += 256 * 4;   // [2][128]

    const int nblkN = (N_NODES + 255) / 256;       // 391
    const int nblkE = (N_EDGES + 255) / 256;       // 6250
    const int nblkG = N_NODES / 32;                // 3125 (gemm, 32 rows/block)
    const int nblkV = (N_NODES + 3) / 4;           // 25000 (gather, 4 nodes/block)
    const int nblkA = (N_NODES * 64) / 256;        // 25000 (bn apply)

    init_kernel<<<nblkN, 256, 0, stream>>>(deg, win, hist, counter, bnacc);
    edge_pass1<<<nblkE, 256, 0, stream>>>(src, dst, attr, deg, win, hist);
    node_alloc<<<nblkN, 256, 0, stream>>>(deg, hist, dinv, start, fpos, counter);
    edge_fill<<<nblkE, 256, 0, stream>>>(src, dst, attr, dinv, fpos, col, nrm);

    // input projection + fused scatter-set node update
    gemm64<0><<<nblkG, 256, 0, stream>>>(x, lin_W, lin_b, h, win, attr, eenc_w, eenc_b);

    for (int l = 0; l < 2; ++l) {
        gemm64<1><<<nblkG, 256, 0, stream>>>(h, conv_W + l * 64 * 64, nullptr, xw,
                                             nullptr, nullptr, nullptr, nullptr);
        gather_kernel<<<nblkV, 256, 0, stream>>>(xw, col, nrm, start, hist, dinv,
                                                 conv_b + l * 64, agg);
        bn_stats<<<512, 256, 0, stream>>>(agg, bnacc + l * 128);
        if (l == 0) {
            bn_apply<1><<<nblkA, 256, 0, stream>>>(agg, bnacc + l * 128,
                                                   gamma + l * 64, beta + l * 64, out, h);
        } else {
            bn_apply<0><<<nblkA, 256, 0, stream>>>(agg, bnacc + l * 128,
                                                   gamma + l * 64, beta + l * 64, out, h);
        }
    }
}

// Round 2
// 663.364 us; speedup vs baseline: 1.1566x; 1.1566x over previous
//
#include <hip/hip_runtime.h>
#include <hip/hip_fp16.h>

#define N_NODES 100000
#define N_EDGES 1600000
#define HID 64
#define BN_EPS 1e-5f
#define NBLK_E 6250      /* N_EDGES / 256 exact */
#define NBLK_G 3125      /* N_NODES / 32 exact */
#define ATTR_INV 1.4901161193847656e-8f   /* 2^-26 */
typedef unsigned long long ull;

// ---------------- init
__global__ void init_kernel(int* win, int* hist, int* counter, float* bnacc) {
    int v = blockIdx.x * blockDim.x + threadIdx.x;
    if (v < N_NODES) { win[v] = -1; hist[v] = 0; }
    if (v == 0) *counter = 0;
    if (v < 256) bnacc[v] = 0.0f;   // [2 layers][sum64|sq64]
}

// ---------------- mega pass 1: edge blocks (2 atomics/edge) + fused h0 GEMM blocks
__launch_bounds__(256)
__global__ void mega_pass1(const int* __restrict__ src, const int* __restrict__ dst,
                           int* __restrict__ win, int* __restrict__ hist,
                           const float* __restrict__ x, const float* __restrict__ lin_W,
                           const float* __restrict__ lin_b, float* __restrict__ h0) {
    __shared__ float xs[2048];
    if (blockIdx.x < NBLK_E) {
        int i = blockIdx.x * 256 + threadIdx.x;   // exact, no tail
        atomicAdd(&hist[dst[i]], 1);
        atomicMax(&win[src[i]], i);               // src-side priority i
        return;
    }
    // ---- GEMM: h0 = x @ lin_W + lin_b (independent of edges)
    int t = threadIdx.x, lane = t & 63, w = t >> 6;
    int base = (blockIdx.x - NBLK_E) * 32;
    const float4* Xv = (const float4*)(x + (size_t)base * 64);
    float4* xsv = (float4*)xs;
    xsv[t] = Xv[t];
    xsv[t + 256] = Xv[t + 256];
    float wc[64];
    #pragma unroll
    for (int k = 0; k < 64; ++k) wc[k] = lin_W[k * 64 + lane];
    __syncthreads();
    float bval = lin_b[lane];
    for (int rr = 0; rr < 8; ++rr) {
        int rl = w * 8 + rr;
        float acc = bval;
        #pragma unroll
        for (int k = 0; k < 64; ++k) acc = fmaf(xs[rl * 64 + k], wc[k], acc);
        h0[(size_t)(base + rl) * 64 + lane] = acc;
    }
}

// ---------------- node alloc: wave scan of hist -> start/fillpos (unordered CSR)
__global__ void node_alloc(const int* __restrict__ hist,
                           int* start, int* fillpos, int* counter) {
    int v = blockIdx.x * blockDim.x + threadIdx.x;
    int lane = threadIdx.x & 63;
    int val = (v < N_NODES) ? hist[v] : 0;
    int xsc = val;
    #pragma unroll
    for (int off = 1; off < 64; off <<= 1) {
        int y = __shfl_up(xsc, off, 64);
        if (lane >= off) xsc += y;
    }
    int total = __shfl(xsc, 63, 64);
    int basep = 0;
    if (lane == 63) basep = atomicAdd(counter, total);
    basep = __shfl(basep, 63, 64);
    if (v < N_NODES) {
        int st = basep + xsc - val;
        start[v] = st;
        fillpos[v] = st;
    }
}

// ---------------- fill: 1 atomic + one packed 8B scattered store per edge
// entry = (edge_idx:21 | src:17 | attr_q26:26)
__global__ void edge_fill(const int* __restrict__ src, const int* __restrict__ dst,
                          const float* __restrict__ attr,
                          int* fillpos, ull* __restrict__ csr) {
    int i = blockIdx.x * 256 + threadIdx.x;   // exact
    int d = dst[i];
    unsigned aq = (unsigned)(attr[i] * 67108864.0f);   // attr in [0,1) -> fits 26 bits
    ull e = ((ull)i << 43) | ((ull)src[i] << 26) | (ull)aq;
    int p = atomicAdd(&fillpos[d], 1);
    csr[p] = e;
}

// ---------------- node finalize: atomic-free deg + dst-winner from CSR
// dinv[v] = rsqrt(1 + sum attr); wa[v] = attr of winning edge or -1
__launch_bounds__(256)
__global__ void node_finalize(const ull* __restrict__ csr, const int* __restrict__ start,
                              const int* __restrict__ hist, const int* __restrict__ win,
                              const float* __restrict__ attr,
                              float* __restrict__ dinv, float* __restrict__ wa) {
    int lane = threadIdx.x & 63, w = threadIdx.x >> 6;
    int v = blockIdx.x * 4 + w;               // 25000 blocks exact
    int s0 = start[v], len = hist[v];
    ull maxe = 0; float sum = 0.0f;
    for (int j = lane; j < len; j += 64) {
        ull e = csr[s0 + j];
        if (e > maxe) maxe = e;
        sum += (float)(e & 0x3FFFFFFull) * ATTR_INV;
    }
    #pragma unroll
    for (int off = 32; off > 0; off >>= 1) {
        sum += __shfl_xor(sum, off, 64);
        ull o = __shfl_xor(maxe, off, 64);
        if (o > maxe) maxe = o;
    }
    if (lane == 0) {
        dinv[v] = rsqrtf(1.0f + sum);
        int wi = (len > 0) ? (int)(maxe >> 43) : win[v];
        wa[v] = (wi >= 0) ? attr[wi] : -1.0f;
    }
}

// ---------------- layer-0 GEMM: stage h0 + apply scatter-set fix, out fp16 xw
__launch_bounds__(256)
__global__ void gemm_l0(const float* __restrict__ h0, const float* __restrict__ W,
                        const float* __restrict__ wa, const float* __restrict__ ew,
                        const float* __restrict__ eb, __half* __restrict__ xw16) {
    __shared__ float xs[2048];
    int t = threadIdx.x, lane = t & 63, w = t >> 6;
    int base = blockIdx.x * 32;
    const float4* Hv = (const float4*)(h0 + (size_t)base * 64);
    #pragma unroll
    for (int q = 0; q < 2; ++q) {
        int idx = t + q * 256;
        int rl = idx >> 4, f0 = (idx & 15) * 4;
        float4 v = Hv[idx];
        float wav = wa[base + rl];
        if (wav >= 0.0f) {
            v.x = fmaxf(fmaf(wav, ew[f0 + 0], v.x + eb[f0 + 0]), 0.0f);
            v.y = fmaxf(fmaf(wav, ew[f0 + 1], v.y + eb[f0 + 1]), 0.0f);
            v.z = fmaxf(fmaf(wav, ew[f0 + 2], v.z + eb[f0 + 2]), 0.0f);
            v.w = fmaxf(fmaf(wav, ew[f0 + 3], v.w + eb[f0 + 3]), 0.0f);
        }
        ((float4*)xs)[idx] = v;
    }
    float wc[64];
    #pragma unroll
    for (int k = 0; k < 64; ++k) wc[k] = W[k * 64 + lane];
    __syncthreads();
    for (int rr = 0; rr < 8; ++rr) {
        int rl = w * 8 + rr;
        float acc = 0.0f;
        #pragma unroll
        for (int k = 0; k < 64; ++k) acc = fmaf(xs[rl * 64 + k], wc[k], acc);
        xw16[(size_t)(base + rl) * 64 + lane] = __float2half(acc);
    }
}

// ---------------- layer-1 GEMM: stage agg0, fuse BN0+relu, write out[:,0:64], out fp16 xw
__launch_bounds__(256)
__global__ void gemm_l1(const float* __restrict__ agg, const float* __restrict__ bnacc,
                        const float* __restrict__ gamma, const float* __restrict__ beta,
                        const float* __restrict__ W, float* __restrict__ out,
                        __half* __restrict__ xw16) {
    __shared__ float xs[2048];
    int t = threadIdx.x, lane = t & 63, w = t >> 6;
    int base = blockIdx.x * 32;
    const float4* Av = (const float4*)(agg + (size_t)base * 64);
    const float invN = 1.0f / (float)N_NODES;
    #pragma unroll
    for (int q = 0; q < 2; ++q) {
        int idx = t + q * 256;
        int rl = idx >> 4, f0 = (idx & 15) * 4;
        float4 v = Av[idx];
        float vv[4] = {v.x, v.y, v.z, v.w};
        #pragma unroll
        for (int c = 0; c < 4; ++c) {
            int f = f0 + c;
            float mean = bnacc[f] * invN;
            float var = bnacc[64 + f] * invN - mean * mean;
            float sc = gamma[f] * rsqrtf(var + BN_EPS);
            float bs = beta[f] - mean * sc;
            vv[c] = fmaxf(fmaf(vv[c], sc, bs), 0.0f);
        }
        float4 r = {vv[0], vv[1], vv[2], vv[3]};
        ((float4*)xs)[idx] = r;
        *(float4*)(out + (size_t)(base + rl) * 128 + f0) = r;   // out[:, 0:64]
    }
    float wc[64];
    #pragma unroll
    for (int k = 0; k < 64; ++k) wc[k] = W[k * 64 + lane];
    __syncthreads();
    for (int rr = 0; rr < 8; ++rr) {
        int rl = w * 8 + rr;
        float acc = 0.0f;
        #pragma unroll
        for (int k = 0; k < 64; ++k) acc = fmaf(xs[rl * 64 + k], wc[k], acc);
        xw16[(size_t)(base + rl) * 64 + lane] = __float2half(acc);
    }
}

// ---------------- gather: agg = conv_b + dinv^2*xw[v] + sum nrm*xw[src]; fused BN stats
// L==0: compute nrm from packed CSR, write csr2 = (nrm:32 | col:32) for layer 1
template<int L>
__launch_bounds__(256)
__global__ void gather_kernel(const __half* __restrict__ xw16, const ull* __restrict__ csr,
                              ull* __restrict__ csr2, const int* __restrict__ start,
                              const int* __restrict__ hist, const float* __restrict__ dinv,
                              const float* __restrict__ convb, float* __restrict__ agg,
                              float* __restrict__ bnacc) {
    int t = threadIdx.x, lane = t & 63, w = t >> 6;
    float cb = convb[lane];
    float bsum = 0.0f, bsq = 0.0f;
    for (int v = blockIdx.x * 4 + w; v < N_NODES; v += gridDim.x * 4) {
        float dv = dinv[v];
        float acc = fmaf(dv * dv, __half2float(xw16[(size_t)v * 64 + lane]), cb);
        float acc2 = 0.0f;
        int s0 = start[v], len = hist[v];
        for (int e0 = 0; e0 < len; e0 += 64) {
            int m = len - e0; if (m > 64) m = 64;
            ull pk = 0;
            if (lane < m) {
                if (L == 0) {
                    ull e = csr[s0 + e0 + lane];
                    int c = (int)((e >> 26) & 0x1FFFFull);
                    float a = (float)(e & 0x3FFFFFFull) * ATTR_INV;
                    float nr = dinv[c] * a * dv;
                    pk = ((ull)__float_as_uint(nr) << 32) | (unsigned)c;
                    csr2[s0 + e0 + lane] = pk;
                } else {
                    pk = csr2[s0 + e0 + lane];
                }
            }
            int j = 0;
            for (; j + 3 < m; j += 4) {
                ull pA = __shfl(pk, j, 64);     ull pB = __shfl(pk, j + 1, 64);
                ull pC = __shfl(pk, j + 2, 64); ull pD = __shfl(pk, j + 3, 64);
                float xA = __half2float(xw16[(size_t)(unsigned)pA * 64 + lane]);
                float xB = __half2float(xw16[(size_t)(unsigned)pB * 64 + lane]);
                float xC = __half2float(xw16[(size_t)(unsigned)pC * 64 + lane]);
                float xD = __half2float(xw16[(size_t)(unsigned)pD * 64 + lane]);
                acc  = fmaf(__uint_as_float((unsigned)(pA >> 32)), xA, acc);
                acc2 = fmaf(__uint_as_float((unsigned)(pB >> 32)), xB, acc2);
                acc  = fmaf(__uint_as_float((unsigned)(pC >> 32)), xC, acc);
                acc2 = fmaf(__uint_as_float((unsigned)(pD >> 32)), xD, acc2);
            }
            for (; j < m; ++j) {
                ull pA = __shfl(pk, j, 64);
                float xA = __half2float(xw16[(size_t)(unsigned)pA * 64 + lane]);
                acc = fmaf(__uint_as_float((unsigned)(pA >> 32)), xA, acc);
            }
        }
        float val = acc + acc2;
        agg[(size_t)v * 64 + lane] = val;
        bsum += val; bsq += val * val;
    }
    __shared__ float red[2][4][64];
    red[0][w][lane] = bsum; red[1][w][lane] = bsq;
    __syncthreads();
    if (w == 0) {
        float s = red[0][0][lane] + red[0][1][lane] + red[0][2][lane] + red[0][3][lane];
        float q = red[1][0][lane] + red[1][1][lane] + red[1][2][lane] + red[1][3][lane];
        atomicAdd(&bnacc[lane], s);
        atomicAdd(&bnacc[64 + lane], q);
    }
}

// ---------------- final BN apply: out[:, 64:128]
__launch_bounds__(256)
__global__ void bn_final(const float* __restrict__ agg, const float* __restrict__ bnacc,
                         const float* __restrict__ gamma, const float* __restrict__ beta,
                         float* __restrict__ out) {
    int idx = blockIdx.x * 256 + threadIdx.x;   // 25000 blocks exact
    int c = idx & 63, v = idx >> 6;
    const float invN = 1.0f / (float)N_NODES;
    float mean = bnacc[c] * invN;
    float var = bnacc[64 + c] * invN - mean * mean;
    float sc = gamma[c] * rsqrtf(var + BN_EPS);
    float bs = beta[c] - mean * sc;
    out[(size_t)v * 128 + 64 + c] = fmaf(agg[idx], sc, bs);
}

extern "C" void kernel_launch(void* const* d_in, const int* in_sizes, int n_in,
                              void* d_out, int out_size, void* d_ws, size_t ws_size,
                              hipStream_t stream) {
    const float* x      = (const float*)d_in[0];
    const int*   eidx   = (const int*)d_in[1];
    const float* attr   = (const float*)d_in[2];
    const float* lin_W  = (const float*)d_in[3];
    const float* lin_b  = (const float*)d_in[4];
    const float* eenc_w = (const float*)d_in[5];
    const float* eenc_b = (const float*)d_in[6];
    const float* conv_W = (const float*)d_in[7];
    const float* conv_b = (const float*)d_in[8];
    const float* gamma  = (const float*)d_in[9];
    const float* beta   = (const float*)d_in[10];
    float* out = (float*)d_out;

    const int* src = eidx;
    const int* dst = eidx + N_EDGES;

    // workspace carve (8B arrays first for alignment)
    char* p = (char*)d_ws;
    ull* csr    = (ull*)p;   p += (size_t)N_EDGES * 8;       // 12.8 MB
    ull* csr2   = (ull*)p;   p += (size_t)N_EDGES * 8;       // 12.8 MB
    float* h0   = (float*)p; p += (size_t)N_NODES * 64 * 4;  // 25.6 MB
    float* agg  = (float*)p; p += (size_t)N_NODES * 64 * 4;  // 25.6 MB
    __half* xw16 = (__half*)p; p += (size_t)N_NODES * 64 * 2; // 12.8 MB
    int* win    = (int*)p;   p += (size_t)N_NODES * 4;
    int* hist   = (int*)p;   p += (size_t)N_NODES * 4;
    int* start  = (int*)p;   p += (size_t)N_NODES * 4;
    int* fpos   = (int*)p;   p += (size_t)N_NODES * 4;
    float* dinv = (float*)p; p += (size_t)N_NODES * 4;
    float* wa   = (float*)p; p += (size_t)N_NODES * 4;
    int* counter = (int*)p;  p += 64;
    float* bnacc = (float*)p; p += 256 * 4;   // [2][128]

    const int nblkN = (N_NODES + 255) / 256;   // 391
    const int nblkF = 25000;                    // node-finalize: 4 nodes/block
    const int GATHER_BLOCKS = 2048;

    init_kernel<<<nblkN, 256, 0, stream>>>(win, hist, counter, bnacc);
    mega_pass1<<<NBLK_E + NBLK_G, 256, 0, stream>>>(src, dst, win, hist,
                                                    x, lin_W, lin_b, h0);
    node_alloc<<<nblkN, 256, 0, stream>>>(hist, start, fpos, counter);
    edge_fill<<<NBLK_E, 256, 0, stream>>>(src, dst, attr, fpos, csr);
    node_finalize<<<nblkF, 256, 0, stream>>>(csr, start, hist, win, attr, dinv, wa);

    // layer 0
    gemm_l0<<<NBLK_G, 256, 0, stream>>>(h0, conv_W, wa, eenc_w, eenc_b, xw16);
    gather_kernel<0><<<GATHER_BLOCKS, 256, 0, stream>>>(xw16, csr, csr2, start, hist,
                                                        dinv, conv_b, agg, bnacc);
    // layer 1 (BN0 fused into staging; writes out[:,0:64])
    gemm_l1<<<NBLK_G, 256, 0, stream>>>(agg, bnacc, gamma, beta,
                                        conv_W + 64 * 64, out, xw16);
    gather_kernel<1><<<GATHER_BLOCKS, 256, 0, stream>>>(xw16, csr, csr2, start, hist,
                                                        dinv, conv_b + 64, agg, bnacc + 128);
    bn_final<<<25000, 256, 0, stream>>>(agg, bnacc + 128, gamma + 64, beta + 64, out);
}

// Round 3
// 538.779 us; speedup vs baseline: 1.4241x; 1.2312x over previous
//
#include <hip/hip_runtime.h>
#include <hip/hip_fp16.h>

#define N_NODES 100000
#define N_EDGES 1600000
#define HID 64
#define BN_EPS 1e-5f
#define NBLK_E 6250      /* N_EDGES / 256 exact */
#define NBLK_G 3125      /* N_NODES / 32 exact */
#define NBLK_N 391       /* ceil(N_NODES/256) */
#define CAP 64           /* bucket capacity per node */
#define OVF_CAP 65536
#define ATTR_INV 1.4901161193847656e-8f   /* 2^-26 */
typedef unsigned long long ull;

// ---------------- init: cnt=0, win=-1, zbitmap=0, flags, bnacc=0
__global__ void init_kernel(int* cnt, int* win, unsigned* zbitmap, int* flags,
                            float* bnacc) {
    int v = blockIdx.x * blockDim.x + threadIdx.x;
    if (v < N_NODES) { cnt[v] = 0; win[v] = -1; }
    if (v < 3125) zbitmap[v] = 0;
    if (v < 2) flags[v] = 0;          // [0]=zany  [1]=ovf_cnt
    if (v < 256) bnacc[v] = 0.0f;     // [2 layers][sum64|sq64]
}

// ---------------- mega edge pass: 1 atomic + 1 packed 8B store per edge,
// fused with h0 = x @ lin_W + lin_b GEMM blocks (edge blocks are VALU-idle)
__launch_bounds__(256)
__global__ void mega_edge(const int* __restrict__ src, const int* __restrict__ dst,
                          const float* __restrict__ attr,
                          int* __restrict__ cnt, ull* __restrict__ bucket,
                          int* __restrict__ flags, int* __restrict__ ovf_d,
                          ull* __restrict__ ovf_e,
                          const float* __restrict__ x, const float* __restrict__ lin_W,
                          const float* __restrict__ lin_b, float* __restrict__ h0) {
    __shared__ float xs[2048];
    if (blockIdx.x < NBLK_E) {
        int i = blockIdx.x * 256 + threadIdx.x;   // exact, no tail
        int d = dst[i];
        unsigned aq = (unsigned)(attr[i] * 67108864.0f);   // attr in [0,1) -> 26 bits
        ull e = ((ull)i << 43) | ((ull)src[i] << 26) | (ull)aq;
        int p = atomicAdd(&cnt[d], 1);
        if (p < CAP) {
            bucket[(size_t)d * CAP + p] = e;
        } else {
            int q = atomicAdd(&flags[1], 1);
            if (q < OVF_CAP) { ovf_d[q] = d; ovf_e[q] = e; }
        }
        return;
    }
    // ---- GEMM blocks: h0 = x @ lin_W + lin_b
    int t = threadIdx.x, lane = t & 63, w = t >> 6;
    int base = (blockIdx.x - NBLK_E) * 32;
    const float4* Xv = (const float4*)(x + (size_t)base * 64);
    float4* xsv = (float4*)xs;
    xsv[t] = Xv[t];
    xsv[t + 256] = Xv[t + 256];
    float wc[64];
    #pragma unroll
    for (int k = 0; k < 64; ++k) wc[k] = lin_W[k * 64 + lane];
    __syncthreads();
    float bval = lin_b[lane];
    for (int rr = 0; rr < 8; ++rr) {
        int rl = w * 8 + rr;
        float acc = bval;
        #pragma unroll
        for (int k = 0; k < 64; ++k) acc = fmaf(xs[rl * 64 + k], wc[k], acc);
        h0[(size_t)(base + rl) * 64 + lane] = acc;
    }
}

// ---------------- node finalize: dinv + dst-winner attr; mark zero-in-degree nodes
__launch_bounds__(256)
__global__ void node_finalize(const ull* __restrict__ bucket, const int* __restrict__ cnt,
                              const int* __restrict__ ovf_d, const ull* __restrict__ ovf_e,
                              int* __restrict__ flags, unsigned* __restrict__ zbitmap,
                              float* __restrict__ dinv, float* __restrict__ wa) {
    int lane = threadIdx.x & 63, w = threadIdx.x >> 6;
    int v = blockIdx.x * 4 + w;               // 25000 blocks exact
    int len = cnt[v];
    int blen = len < CAP ? len : CAP;
    ull maxe = 0; float sum = 0.0f;
    const ull* b = bucket + (size_t)v * CAP;
    for (int j = lane; j < blen; j += 64) {
        ull e = b[j];
        if (e > maxe) maxe = e;
        sum += (float)(e & 0x3FFFFFFull) * ATTR_INV;
    }
    if (len > CAP) {                           // overflow scan (never taken in practice)
        int oc = flags[1]; if (oc > OVF_CAP) oc = OVF_CAP;
        for (int j = lane; j < oc; j += 64) {
            if (ovf_d[j] == v) {
                ull e = ovf_e[j];
                if (e > maxe) maxe = e;
                sum += (float)(e & 0x3FFFFFFull) * ATTR_INV;
            }
        }
    }
    #pragma unroll
    for (int off = 32; off > 0; off >>= 1) {
        sum += __shfl_xor(sum, off, 64);
        ull o = __shfl_xor(maxe, off, 64);
        if (o > maxe) maxe = o;
    }
    if (lane == 0) {
        dinv[v] = rsqrtf(1.0f + sum);
        if (len > 0) {
            wa[v] = (float)(maxe & 0x3FFFFFFull) * ATTR_INV;   // quantized attr, err 1.5e-8
        } else {
            wa[v] = -1.0f;
            atomicOr(&zbitmap[v >> 5], 1u << (v & 31));
            flags[0] = 1;                      // zany (racy set-to-1 is fine)
        }
    }
}

// ---------------- fixup scan: src-side winner for zero-in-degree nodes (early-exit)
__global__ void fixup_scan(const int* __restrict__ src, const int* __restrict__ flags,
                           const unsigned* __restrict__ zbitmap, int* __restrict__ win) {
    if (flags[0] == 0) return;
    int i = blockIdx.x * 256 + threadIdx.x;
    int s = src[i];
    if ((zbitmap[s >> 5] >> (s & 31)) & 1u) atomicMax(&win[s], i);
}

// ---------------- fixup apply: wa for zero-in-degree nodes that have out-edges
__global__ void fixup_apply(const int* __restrict__ flags, const unsigned* __restrict__ zbitmap,
                            const int* __restrict__ win, const float* __restrict__ attr,
                            float* __restrict__ wa) {
    if (flags[0] == 0) return;
    int v = blockIdx.x * 256 + threadIdx.x;
    if (v >= N_NODES) return;
    if (((zbitmap[v >> 5] >> (v & 31)) & 1u) && win[v] >= 0) wa[v] = attr[win[v]];
}

// ---------------- layer-0 GEMM: stage h0 + scatter-set fix, out fp16 xw
__launch_bounds__(256)
__global__ void gemm_l0(const float* __restrict__ h0, const float* __restrict__ W,
                        const float* __restrict__ wa, const float* __restrict__ ew,
                        const float* __restrict__ eb, __half* __restrict__ xw16) {
    __shared__ float xs[2048];
    int t = threadIdx.x, lane = t & 63, w = t >> 6;
    int base = blockIdx.x * 32;
    const float4* Hv = (const float4*)(h0 + (size_t)base * 64);
    #pragma unroll
    for (int q = 0; q < 2; ++q) {
        int idx = t + q * 256;
        int rl = idx >> 4, f0 = (idx & 15) * 4;
        float4 v = Hv[idx];
        float wav = wa[base + rl];
        if (wav >= 0.0f) {
            v.x = fmaxf(fmaf(wav, ew[f0 + 0], v.x + eb[f0 + 0]), 0.0f);
            v.y = fmaxf(fmaf(wav, ew[f0 + 1], v.y + eb[f0 + 1]), 0.0f);
            v.z = fmaxf(fmaf(wav, ew[f0 + 2], v.z + eb[f0 + 2]), 0.0f);
            v.w = fmaxf(fmaf(wav, ew[f0 + 3], v.w + eb[f0 + 3]), 0.0f);
        }
        ((float4*)xs)[idx] = v;
    }
    float wc[64];
    #pragma unroll
    for (int k = 0; k < 64; ++k) wc[k] = W[k * 64 + lane];
    __syncthreads();
    for (int rr = 0; rr < 8; ++rr) {
        int rl = w * 8 + rr;
        float acc = 0.0f;
        #pragma unroll
        for (int k = 0; k < 64; ++k) acc = fmaf(xs[rl * 64 + k], wc[k], acc);
        xw16[(size_t)(base + rl) * 64 + lane] = __float2half(acc);
    }
}

// ---------------- layer-1 GEMM: stage agg0 + BN0 + relu, write out[:,0:64], fp16 xw
__launch_bounds__(256)
__global__ void gemm_l1(const float* __restrict__ agg, const float* __restrict__ bnacc,
                        const float* __restrict__ gamma, const float* __restrict__ beta,
                        const float* __restrict__ W, float* __restrict__ out,
                        __half* __restrict__ xw16) {
    __shared__ float xs[2048];
    int t = threadIdx.x, lane = t & 63, w = t >> 6;
    int base = blockIdx.x * 32;
    const float4* Av = (const float4*)(agg + (size_t)base * 64);
    const float invN = 1.0f / (float)N_NODES;
    #pragma unroll
    for (int q = 0; q < 2; ++q) {
        int idx = t + q * 256;
        int rl = idx >> 4, f0 = (idx & 15) * 4;
        float4 v = Av[idx];
        float vv[4] = {v.x, v.y, v.z, v.w};
        #pragma unroll
        for (int c = 0; c < 4; ++c) {
            int f = f0 + c;
            float mean = bnacc[f] * invN;
            float var = bnacc[64 + f] * invN - mean * mean;
            float sc = gamma[f] * rsqrtf(var + BN_EPS);
            float bs = beta[f] - mean * sc;
            vv[c] = fmaxf(fmaf(vv[c], sc, bs), 0.0f);
        }
        float4 r = {vv[0], vv[1], vv[2], vv[3]};
        ((float4*)xs)[idx] = r;
        *(float4*)(out + (size_t)(base + rl) * 128 + f0) = r;   // out[:, 0:64]
    }
    float wc[64];
    #pragma unroll
    for (int k = 0; k < 64; ++k) wc[k] = W[k * 64 + lane];
    __syncthreads();
    for (int rr = 0; rr < 8; ++rr) {
        int rl = w * 8 + rr;
        float acc = 0.0f;
        #pragma unroll
        for (int k = 0; k < 64; ++k) acc = fmaf(xs[rl * 64 + k], wc[k], acc);
        xw16[(size_t)(base + rl) * 64 + lane] = __float2half(acc);
    }
}

// ---------------- gather: agg = conv_b + dinv^2*xw[v] + sum nrm*xw[src]; fused BN stats
// L==0: decode (idx|src|attrq), compute nrm, REWRITE bucket slot in place as (nrm|col)
template<int L>
__launch_bounds__(256)
__global__ void gather_kernel(const __half* __restrict__ xw16, ull* __restrict__ bucket,
                              const int* __restrict__ cnt, const int* __restrict__ flags,
                              const int* __restrict__ ovf_d, ull* __restrict__ ovf_e,
                              const float* __restrict__ dinv,
                              const float* __restrict__ convb, float* __restrict__ agg,
                              float* __restrict__ bnacc) {
    int t = threadIdx.x, lane = t & 63, w = t >> 6;
    float cb = convb[lane];
    float bsum = 0.0f, bsq = 0.0f;
    for (int v = blockIdx.x * 4 + w; v < N_NODES; v += gridDim.x * 4) {
        float dv = dinv[v];
        float acc = fmaf(dv * dv, __half2float(xw16[(size_t)v * 64 + lane]), cb);
        float acc2 = 0.0f;
        int len = cnt[v];
        int blen = len < CAP ? len : CAP;
        ull* b = bucket + (size_t)v * CAP;
        for (int e0 = 0; e0 < blen; e0 += 64) {
            int m = blen - e0; if (m > 64) m = 64;
            ull pk = 0;
            if (lane < m) {
                if (L == 0) {
                    ull e = b[e0 + lane];
                    int c = (int)((e >> 26) & 0x1FFFFull);
                    float a = (float)(e & 0x3FFFFFFull) * ATTR_INV;
                    float nr = dinv[c] * a * dv;
                    pk = ((ull)__float_as_uint(nr) << 32) | (unsigned)c;
                    b[e0 + lane] = pk;
                } else {
                    pk = b[e0 + lane];
                }
            }
            int j = 0;
            for (; j + 3 < m; j += 4) {
                ull pA = __shfl(pk, j, 64);     ull pB = __shfl(pk, j + 1, 64);
                ull pC = __shfl(pk, j + 2, 64); ull pD = __shfl(pk, j + 3, 64);
                float xA = __half2float(xw16[(size_t)(unsigned)pA * 64 + lane]);
                float xB = __half2float(xw16[(size_t)(unsigned)pB * 64 + lane]);
                float xC = __half2float(xw16[(size_t)(unsigned)pC * 64 + lane]);
                float xD = __half2float(xw16[(size_t)(unsigned)pD * 64 + lane]);
                acc  = fmaf(__uint_as_float((unsigned)(pA >> 32)), xA, acc);
                acc2 = fmaf(__uint_as_float((unsigned)(pB >> 32)), xB, acc2);
                acc  = fmaf(__uint_as_float((unsigned)(pC >> 32)), xC, acc);
                acc2 = fmaf(__uint_as_float((unsigned)(pD >> 32)), xD, acc2);
            }
            for (; j < m; ++j) {
                ull pA = __shfl(pk, j, 64);
                float xA = __half2float(xw16[(size_t)(unsigned)pA * 64 + lane]);
                acc = fmaf(__uint_as_float((unsigned)(pA >> 32)), xA, acc);
            }
        }
        if (len > CAP) {                       // overflow (never taken in practice)
            int oc = flags[1]; if (oc > OVF_CAP) oc = OVF_CAP;
            for (int j = 0; j < oc; ++j) {
                int d = ovf_d[j];
                if (d != v) continue;
                ull pk;
                if (L == 0) {
                    ull e = ovf_e[j];
                    int c = (int)((e >> 26) & 0x1FFFFull);
                    float a = (float)(e & 0x3FFFFFFull) * ATTR_INV;
                    float nr = dinv[c] * a * dv;
                    pk = ((ull)__float_as_uint(nr) << 32) | (unsigned)c;
                    if (lane == 0) ovf_e[j] = pk;
                } else {
                    pk = ovf_e[j];
                }
                float xA = __half2float(xw16[(size_t)(unsigned)pk * 64 + lane]);
                acc = fmaf(__uint_as_float((unsigned)(pk >> 32)), xA, acc);
            }
        }
        float val = acc + acc2;
        agg[(size_t)v * 64 + lane] = val;
        bsum += val; bsq += val * val;
    }
    __shared__ float red[2][4][64];
    red[0][w][lane] = bsum; red[1][w][lane] = bsq;
    __syncthreads();
    if (w == 0) {
        float s = red[0][0][lane] + red[0][1][lane] + red[0][2][lane] + red[0][3][lane];
        float q = red[1][0][lane] + red[1][1][lane] + red[1][2][lane] + red[1][3][lane];
        atomicAdd(&bnacc[lane], s);
        atomicAdd(&bnacc[64 + lane], q);
    }
}

// ---------------- final BN apply: out[:, 64:128]
__launch_bounds__(256)
__global__ void bn_final(const float* __restrict__ agg, const float* __restrict__ bnacc,
                         const float* __restrict__ gamma, const float* __restrict__ beta,
                         float* __restrict__ out) {
    int idx = blockIdx.x * 256 + threadIdx.x;   // 25000 blocks exact
    int c = idx & 63, v = idx >> 6;
    const float invN = 1.0f / (float)N_NODES;
    float mean = bnacc[c] * invN;
    float var = bnacc[64 + c] * invN - mean * mean;
    float sc = gamma[c] * rsqrtf(var + BN_EPS);
    float bs = beta[c] - mean * sc;
    out[(size_t)v * 128 + 64 + c] = fmaf(agg[idx], sc, bs);
}

extern "C" void kernel_launch(void* const* d_in, const int* in_sizes, int n_in,
                              void* d_out, int out_size, void* d_ws, size_t ws_size,
                              hipStream_t stream) {
    const float* x      = (const float*)d_in[0];
    const int*   eidx   = (const int*)d_in[1];
    const float* attr   = (const float*)d_in[2];
    const float* lin_W  = (const float*)d_in[3];
    const float* lin_b  = (const float*)d_in[4];
    const float* eenc_w = (const float*)d_in[5];
    const float* eenc_b = (const float*)d_in[6];
    const float* conv_W = (const float*)d_in[7];
    const float* conv_b = (const float*)d_in[8];
    const float* gamma  = (const float*)d_in[9];
    const float* beta   = (const float*)d_in[10];
    float* out = (float*)d_out;

    const int* src = eidx;
    const int* dst = eidx + N_EDGES;

    // workspace carve (~92 MB)
    char* p = (char*)d_ws;
    ull* bucket = (ull*)p;   p += (size_t)N_NODES * CAP * 8;   // 51.2 MB
    ull* ovf_e  = (ull*)p;   p += (size_t)OVF_CAP * 8;         // 0.5 MB
    float* h0   = (float*)p; p += (size_t)N_NODES * 64 * 4;    // 25.6 MB (aliased: agg)
    __half* xw16 = (__half*)p; p += (size_t)N_NODES * 64 * 2;  // 12.8 MB
    int* cnt    = (int*)p;   p += (size_t)N_NODES * 4;
    float* dinv = (float*)p; p += (size_t)N_NODES * 4;
    float* wa   = (float*)p; p += (size_t)N_NODES * 4;
    int* win    = (int*)p;   p += (size_t)N_NODES * 4;
    int* ovf_d  = (int*)p;   p += (size_t)OVF_CAP * 4;         // 0.25 MB
    unsigned* zbitmap = (unsigned*)p; p += 3125 * 4 + 12;
    int* flags  = (int*)p;   p += 64;                          // [0]=zany [1]=ovf_cnt
    float* bnacc = (float*)p; p += 256 * 4;                    // [2][128]
    float* agg = h0;   // alias: h0 dead after gemm_l0, agg written by gather<0> after

    init_kernel<<<NBLK_N, 256, 0, stream>>>(cnt, win, zbitmap, flags, bnacc);
    mega_edge<<<NBLK_E + NBLK_G, 256, 0, stream>>>(src, dst, attr, cnt, bucket,
                                                   flags, ovf_d, ovf_e,
                                                   x, lin_W, lin_b, h0);
    node_finalize<<<25000, 256, 0, stream>>>(bucket, cnt, ovf_d, ovf_e,
                                             flags, zbitmap, dinv, wa);
    fixup_scan<<<NBLK_E, 256, 0, stream>>>(src, flags, zbitmap, win);
    fixup_apply<<<NBLK_N, 256, 0, stream>>>(flags, zbitmap, win, attr, wa);

    // layer 0
    gemm_l0<<<NBLK_G, 256, 0, stream>>>(h0, conv_W, wa, eenc_w, eenc_b, xw16);
    gather_kernel<0><<<2048, 256, 0, stream>>>(xw16, bucket, cnt, flags, ovf_d, ovf_e,
                                               dinv, conv_b, agg, bnacc);
    // layer 1 (BN0 fused into staging; writes out[:,0:64])
    gemm_l1<<<NBLK_G, 256, 0, stream>>>(agg, bnacc, gamma, beta,
                                        conv_W + 64 * 64, out, xw16);
    gather_kernel<1><<<2048, 256, 0, stream>>>(xw16, bucket, cnt, flags, ovf_d, ovf_e,
                                               dinv, conv_b + 64, agg, bnacc + 128);
    bn_final<<<25000, 256, 0, stream>>>(agg, bnacc + 128, gamma + 64, beta + 64, out);
}